// Round 7
// baseline (493.924 us; speedup 1.0000x reference)
//
#include <hip/hip_runtime.h>

typedef unsigned short u16;
typedef unsigned int u32;
typedef __attribute__((ext_vector_type(8))) short short8;
typedef __attribute__((ext_vector_type(4))) short short4v;
typedef __attribute__((ext_vector_type(4))) float f32x4;

__device__ __forceinline__ u16 f2bf(float f) {
  union { float f; u32 u; } v; v.f = f;
  u32 u = v.u;
  u32 r = (u + 0x7fffu + ((u >> 16) & 1u)) >> 16;
  return (u16)r;
}

// async global->LDS, 16 B per lane; lds base wave-uniform, lane i -> lds+i*16B.
__device__ __forceinline__ void async_ld16(const u16* g, u16* l) {
  __builtin_amdgcn_global_load_lds(
      (const __attribute__((address_space(1))) void*)g,
      (__attribute__((address_space(3))) void*)l, 16, 0, 0);
}

// ---- fused prep: [0,8192) q-conv | [8192,9216) k/v slice conv | [9216,13312) 4 transposes
__global__ __launch_bounds__(256) void prep(
    const float* __restrict__ q, const float* __restrict__ qm,
    const float* __restrict__ k, const float* __restrict__ km,
    const float* __restrict__ v, const float* __restrict__ vm,
    const float* __restrict__ wq, const float* __restrict__ wk,
    const float* __restrict__ wv, const float* __restrict__ wo,
    u16* __restrict__ Qc, u16* __restrict__ Kc, u16* __restrict__ Vc,
    u16* __restrict__ WqT, u16* __restrict__ WkT, u16* __restrict__ WvT,
    u16* __restrict__ WoT) {
  __shared__ u16 tile[32][33];
  const int bid = blockIdx.x;
  const int tid = threadIdx.x;
  if (bid < 8192) {
    // q * mask -> bf16
    int i = (bid * 256 + tid) * 4;
    float m = qm[i >> 10];
    float4 vv = *(const float4*)(q + i);
    short4v o;
    o.x = (short)f2bf(vv.x * m);
    o.y = (short)f2bf(vv.y * m);
    o.z = (short)f2bf(vv.z * m);
    o.w = (short)f2bf(vv.w * m);
    *(short4v*)(Qc + i) = o;
  } else if (bid < 9216) {
    // k&v rows [1920,2048) per batch, * mask -> bf16
    int zb = bid - 8192;
    int z = zb >> 9;  // 0=k, 1=v (512 blocks each)
    int bx = zb & 511;
    const float* src = z ? v : k;
    const float* mask = z ? vm : km;
    u16* dst = z ? Vc : Kc;
    int i = (bx * 256 + tid) * 4;
    int r = i >> 10, c = i & 1023;
    size_t sr = (size_t)(r >> 7) * 2048 + 1920 + (r & 127);
    float m = mask[sr];
    float4 vv = *(const float4*)(src + sr * 1024 + c);
    short4v o;
    o.x = (short)f2bf(vv.x * m);
    o.y = (short)f2bf(vv.y * m);
    o.z = (short)f2bf(vv.z * m);
    o.w = (short)f2bf(vv.w * m);
    *(short4v*)(dst + i) = o;
  } else {
    // weight transpose: WT[n][k] = bf16(W[k][n]); 1024 blocks per weight
    int idx = bid - 9216;
    int z = idx >> 10;
    int rem = idx & 1023;
    const float* W = (z == 0) ? wq : (z == 1) ? wk : (z == 2) ? wv : wo;
    u16* WT = (z == 0) ? WqT : (z == 1) ? WkT : (z == 2) ? WvT : WoT;
    int tx = tid & 31, ty = tid >> 5;
    int x = (rem & 31) * 32 + tx;
    int y0 = (rem >> 5) * 32;
    for (int i = ty; i < 32; i += 8)
      tile[i][tx] = f2bf(W[(size_t)(y0 + i) * 1024 + x]);
    __syncthreads();
    int x2 = y0 + tx;
    int r0 = (rem & 31) * 32;
    for (int i = ty; i < 32; i += 8)
      WT[(size_t)(r0 + i) * 1024 + x2] = tile[tx][i];
  }
}

// ---- m97-style 128x128 tiled GEMM body: C = A @ BT^T + bias ----
// outmode 0: bf16 C[r*N+c] ; 1: bf16 FK (b,h,l,d) ; 2: bf16 FVT (b,h,d,l) ;
// 3: fp32 C[r*N+c]
__device__ __forceinline__ void gemm_body(
    const u16* __restrict__ A, const u16* __restrict__ BT,
    const float* __restrict__ bias, void* __restrict__ Cv, int N, int K,
    int outmode, int bx, int by) {
  __shared__ u16 As[128 * 32];  // [row][k], BK=32
  __shared__ u16 Bs[128 * 32];  // [col][k]
  const int wave = threadIdx.x >> 6, lane = threadIdx.x & 63;
  const int ln = lane & 15, quad = lane >> 4;
  const int w0 = wave & 1, w1 = wave >> 1;
  const int row0 = bx * 128;
  const int col0 = by * 128;
  const int srow = lane >> 2, scol = (lane & 3) * 8;
  const u16* gA = A + (size_t)(row0 + wave * 32 + srow) * K + scol;
  const u16* gB = BT + (size_t)(col0 + wave * 32 + srow) * K + scol;
  u16* lA = &As[(wave * 32) * 32];
  u16* lB = &Bs[(wave * 32) * 32];

  f32x4 acc[4][4];
  for (int i = 0; i < 4; ++i)
    for (int j = 0; j < 4; ++j) acc[i][j] = f32x4{0.f, 0.f, 0.f, 0.f};

  for (int k0 = 0; k0 < K; k0 += 32) {
    async_ld16(gA + k0, lA);
    async_ld16(gA + (size_t)16 * K + k0, lA + 16 * 32);
    async_ld16(gB + k0, lB);
    async_ld16(gB + (size_t)16 * K + k0, lB + 16 * 32);
    __syncthreads();
    short8 af[4], bf[4];
    for (int mt = 0; mt < 4; ++mt)
      af[mt] = *(const short8*)&As[(w1 * 64 + mt * 16 + ln) * 32 + quad * 8];
    for (int nt = 0; nt < 4; ++nt)
      bf[nt] = *(const short8*)&Bs[(w0 * 64 + nt * 16 + ln) * 32 + quad * 8];
    for (int mt = 0; mt < 4; ++mt)
      for (int nt = 0; nt < 4; ++nt)
        acc[mt][nt] = __builtin_amdgcn_mfma_f32_16x16x32_bf16(af[mt], bf[nt],
                                                              acc[mt][nt], 0, 0, 0);
    __syncthreads();
  }

  for (int nt = 0; nt < 4; ++nt) {
    int c = col0 + w0 * 64 + nt * 16 + ln;
    float bval = bias ? bias[c] : 0.f;
    for (int mt = 0; mt < 4; ++mt)
      for (int reg = 0; reg < 4; ++reg) {
        int r = row0 + w1 * 64 + mt * 16 + quad * 4 + reg;
        float val = acc[mt][nt][reg] + bval;
        if (outmode == 3) {
          ((float*)Cv)[(size_t)r * N + c] = val;
        } else if (outmode == 0) {
          ((u16*)Cv)[(size_t)r * N + c] = f2bf(val);
        } else {
          size_t idx = (outmode == 1)
                           ? (((size_t)(r >> 7) << 17) + ((size_t)(c >> 6) << 13) +
                              ((size_t)(r & 127) << 6) + (c & 63))
                           : (((size_t)(r >> 7) << 17) + ((size_t)(c >> 6) << 13) +
                              ((size_t)(c & 63) << 7) + (r & 127));
          ((u16*)Cv)[idx] = f2bf(val);
        }
      }
  }
}

// Fused Q/K/V projection launch: 576 blocks, XCD-swizzled (576 % 8 == 0).
// swizzled id < 512 -> Q tile (64x8); else 64 K/V tiles (z: 0=K, 1=V).
__global__ __launch_bounds__(256) void proj(
    const u16* __restrict__ Qc, const u16* __restrict__ Kc,
    const u16* __restrict__ Vc, const u16* __restrict__ WqT,
    const u16* __restrict__ WkT, const u16* __restrict__ WvT,
    const float* __restrict__ bq, const float* __restrict__ bk,
    const float* __restrict__ bv, u16* __restrict__ Qws, u16* __restrict__ FK,
    u16* __restrict__ FVT) {
  int orig = blockIdx.x;                     // [0,576)
  int id = (orig & 7) * 72 + (orig >> 3);    // bijective XCD swizzle
  bool isQ = id < 512;
  int t = isQ ? 0 : id - 512;                // [0,64)
  int z = t >> 5;                            // 0=K, 1=V
  const u16* A = isQ ? Qc : (z ? Vc : Kc);
  const u16* BT = isQ ? WqT : (z ? WvT : WkT);
  const float* bias = isQ ? bq : (z ? bv : bk);
  void* Cv = isQ ? (void*)Qws : (z ? (void*)FVT : (void*)FK);
  int outmode = isQ ? 0 : (z ? 2 : 1);
  int bx = isQ ? (id >> 3) : ((t & 31) >> 3);
  int by = isQ ? (id & 7) : (t & 7);
  gemm_body(A, BT, bias, Cv, 1024, 1024, outmode, bx, by);
}

// Output projection: 512 blocks linear, XCD-swizzled (512 % 8 == 0).
__global__ __launch_bounds__(256) void gemm_o(const u16* __restrict__ A,
                                              const u16* __restrict__ BT,
                                              const float* __restrict__ bias,
                                              float* __restrict__ C) {
  int orig = blockIdx.x;                   // [0,512)
  int id = (orig & 7) * 64 + (orig >> 3);  // bijective XCD swizzle
  gemm_body(A, BT, bias, C, 1024, 1024, 3, id >> 3, id & 7);
}

// Fused attention: per (b,h) and 16-row Q tile (4 tiles/block), no barriers.
__global__ __launch_bounds__(256) void attn_kernel(
    const u16* __restrict__ Q, const u16* __restrict__ FK,
    const u16* __restrict__ FVT, float* __restrict__ attn_out,
    u16* __restrict__ OUTP) {
  __shared__ float lds[4][16 * 132];  // P, padded row stride 132 (2-way max)
  const int wave = threadIdx.x >> 6, lane = threadIdx.x & 63;
  const int ln = lane & 15, quad = lane >> 4;
  const int bh = blockIdx.x, b = bh >> 4, h = bh & 15;
  const int q0 = blockIdx.y * 64 + wave * 16;

  const u16* qp = Q + (size_t)(b * 2048 + q0 + ln) * 1024 + h * 64 + quad * 8;
  const u16* fk = FK + ((size_t)bh << 13);
  const u16* fvt = FVT + ((size_t)bh << 13);

  f32x4 acc[8];
  for (int i = 0; i < 8; ++i) acc[i] = f32x4{0.f, 0.f, 0.f, 0.f};
  for (int ks = 0; ks < 2; ++ks) {
    short8 a = *(const short8*)(qp + ks * 32);
    __builtin_amdgcn_s_setprio(1);
    for (int nt = 0; nt < 8; ++nt) {
      short8 bfrag = *(const short8*)(fk + (size_t)(nt * 16 + ln) * 64 +
                                      ks * 32 + quad * 8);
      acc[nt] = __builtin_amdgcn_mfma_f32_16x16x32_bf16(a, bfrag, acc[nt], 0, 0, 0);
    }
    __builtin_amdgcn_s_setprio(0);
  }
  float mx[4] = {-3e38f, -3e38f, -3e38f, -3e38f};
  for (int nt = 0; nt < 8; ++nt) {
    int l = nt * 16 + ln;
    for (int reg = 0; reg < 4; ++reg) {
      int qg = q0 + quad * 4 + reg;
      float vv = acc[nt][reg] * 0.125f;
      if (l > qg) vv = -1e9f;
      acc[nt][reg] = vv;
      mx[reg] = fmaxf(mx[reg], vv);
    }
  }
  for (int off = 1; off < 16; off <<= 1)
    for (int reg = 0; reg < 4; ++reg)
      mx[reg] = fmaxf(mx[reg], __shfl_xor(mx[reg], off, 64));
  float sm[4] = {0.f, 0.f, 0.f, 0.f};
  for (int nt = 0; nt < 8; ++nt)
    for (int reg = 0; reg < 4; ++reg) {
      float p = __expf(acc[nt][reg] - mx[reg]);
      acc[nt][reg] = p;
      sm[reg] += p;
    }
  for (int off = 1; off < 16; off <<= 1)
    for (int reg = 0; reg < 4; ++reg) sm[reg] += __shfl_xor(sm[reg], off, 64);
  float inv[4];
  for (int reg = 0; reg < 4; ++reg) inv[reg] = 1.f / sm[reg];
  // P -> LDS (wave-local; padded stride kills 4-way write conflicts)
  for (int nt = 0; nt < 8; ++nt)
    for (int reg = 0; reg < 4; ++reg)
      lds[wave][(quad * 4 + reg) * 132 + nt * 16 + ln] = acc[nt][reg] * inv[reg];
  // attn output (fp32), vectorized from LDS
  {
    int r = lane >> 2, cb = (lane & 3) * 32;
    const float* lrow = &lds[wave][r * 132 + cb];
    float* dst = attn_out + ((size_t)bh * 2048 + q0 + r) * 128 + cb;
    for (int vblk = 0; vblk < 8; ++vblk)
      *(float4*)(dst + vblk * 4) = *(const float4*)(lrow + vblk * 4);
  }
  // PV: out(16x64) = P(16x128) @ FV(128x64)
  f32x4 o[4];
  for (int i = 0; i < 4; ++i) o[i] = f32x4{0.f, 0.f, 0.f, 0.f};
  for (int kk = 0; kk < 4; ++kk) {
    const float* apf = &lds[wave][ln * 132 + kk * 32 + quad * 8];
    float2 f01 = *(const float2*)(apf + 0);
    float2 f23 = *(const float2*)(apf + 2);
    float2 f45 = *(const float2*)(apf + 4);
    float2 f67 = *(const float2*)(apf + 6);
    short8 a;
    a[0] = (short)f2bf(f01.x);
    a[1] = (short)f2bf(f01.y);
    a[2] = (short)f2bf(f23.x);
    a[3] = (short)f2bf(f23.y);
    a[4] = (short)f2bf(f45.x);
    a[5] = (short)f2bf(f45.y);
    a[6] = (short)f2bf(f67.x);
    a[7] = (short)f2bf(f67.y);
    __builtin_amdgcn_s_setprio(1);
    for (int nt = 0; nt < 4; ++nt) {
      short8 bfrag = *(const short8*)(fvt + (size_t)(nt * 16 + ln) * 128 +
                                      kk * 32 + quad * 8);
      o[nt] = __builtin_amdgcn_mfma_f32_16x16x32_bf16(a, bfrag, o[nt], 0, 0, 0);
    }
    __builtin_amdgcn_s_setprio(0);
  }
  // stage o as bf16 in (reused) wave-local LDS, stride 72 u16 (16B-aligned rows)
  {
    u16* ot = (u16*)&lds[wave][0];
    for (int nt = 0; nt < 4; ++nt)
      for (int reg = 0; reg < 4; ++reg)
        ot[(quad * 4 + reg) * 72 + nt * 16 + ln] = f2bf(o[nt][reg]);
    int row = lane >> 2;
    u16* dst = OUTP + (size_t)(b * 2048 + q0 + row) * 1024 + h * 64;
    for (int p = 0; p < 2; ++p) {
      int col = p * 32 + (lane & 3) * 8;
      *(short8*)(dst + col) = *(const short8*)&ot[row * 72 + col];
    }
  }
}

extern "C" void kernel_launch(void* const* d_in, const int* in_sizes, int n_in,
                              void* d_out, int out_size, void* d_ws,
                              size_t ws_size, hipStream_t stream) {
  const float* q = (const float*)d_in[0];
  const float* k = (const float*)d_in[1];
  const float* v = (const float*)d_in[2];
  const float* qm = (const float*)d_in[3];
  const float* km = (const float*)d_in[4];
  const float* vm = (const float*)d_in[5];
  const float* wq = (const float*)d_in[6];
  const float* bq = (const float*)d_in[7];
  const float* wk = (const float*)d_in[8];
  const float* bk = (const float*)d_in[9];
  const float* wv = (const float*)d_in[10];
  const float* bv = (const float*)d_in[11];
  const float* wo = (const float*)d_in[12];
  const float* bo = (const float*)d_in[13];
  float* out = (float*)d_out;                       // (4,2048,1024) fp32
  float* attn_out = out + (size_t)4 * 2048 * 1024;  // (4,16,2048,128) fp32

  char* ws = (char*)d_ws;
  const size_t MB = 1ull << 20;
  u16* WqT = (u16*)(ws + 0 * MB);
  u16* WkT = (u16*)(ws + 2 * MB);
  u16* WvT = (u16*)(ws + 4 * MB);
  u16* WoT = (u16*)(ws + 6 * MB);
  u16* Qws = (u16*)(ws + 8 * MB);    // 16 MB projected Q bf16
  u16* FKw = (u16*)(ws + 24 * MB);   // 1 MB (b,h,l,d)
  u16* FVTw = (u16*)(ws + 25 * MB);  // 1 MB (b,h,d,l)
  u16* OUTP = (u16*)(ws + 26 * MB);  // 16 MB pre-Wo bf16; aliased as Qc first
  u16* Qc = OUTP;                    // dead before OUTP written
  u16* Kc = (u16*)(ws + 42 * MB);
  u16* Vc = (u16*)(ws + 43 * MB);

  prep<<<13312, 256, 0, stream>>>(q, qm, k, km, v, vm, wq, wk, wv, wo, Qc, Kc,
                                  Vc, WqT, WkT, WvT, WoT);
  // Q + K + V projections in ONE launch (576 blocks: 512 Q tiles + 64 KV tiles)
  proj<<<576, 256, 0, stream>>>(Qc, Kc, Vc, WqT, WkT, WvT, bq, bk, bv, Qws,
                                FKw, FVTw);
  attn_kernel<<<dim3(64, 32), 256, 0, stream>>>(Qws, FKw, FVTw, attn_out, OUTP);
  // Output projection -> fp32 output 0
  gemm_o<<<512, 256, 0, stream>>>(OUTP, WoT, bo, out);
}

// Round 8
// 298.473 us; speedup vs baseline: 1.6548x; 1.6548x over previous
//
#include <hip/hip_runtime.h>

typedef unsigned short u16;
typedef unsigned int u32;
typedef __attribute__((ext_vector_type(8))) short short8;
typedef __attribute__((ext_vector_type(4))) short short4v;
typedef __attribute__((ext_vector_type(4))) float f32x4;

__device__ __forceinline__ u16 f2bf(float f) {
  union { float f; u32 u; } v; v.f = f;
  u32 u = v.u;
  u32 r = (u + 0x7fffu + ((u >> 16) & 1u)) >> 16;
  return (u16)r;
}

// async global->LDS, 16 B per lane; lds base wave-uniform, lane i -> lds+i*16B.
__device__ __forceinline__ void async_ld16(const u16* g, u16* l) {
  __builtin_amdgcn_global_load_lds(
      (const __attribute__((address_space(1))) void*)g,
      (__attribute__((address_space(3))) void*)l, 16, 0, 0);
}

// ---- fused prep: [0,8192) q-conv | [8192,9216) k/v slice conv | [9216,13312) 4 transposes
__global__ __launch_bounds__(256) void prep(
    const float* __restrict__ q, const float* __restrict__ qm,
    const float* __restrict__ k, const float* __restrict__ km,
    const float* __restrict__ v, const float* __restrict__ vm,
    const float* __restrict__ wq, const float* __restrict__ wk,
    const float* __restrict__ wv, const float* __restrict__ wo,
    u16* __restrict__ Qc, u16* __restrict__ Kc, u16* __restrict__ Vc,
    u16* __restrict__ WqT, u16* __restrict__ WkT, u16* __restrict__ WvT,
    u16* __restrict__ WoT) {
  __shared__ u16 tile[32][33];
  const int bid = blockIdx.x;
  const int tid = threadIdx.x;
  if (bid < 8192) {
    // q * mask -> bf16
    int i = (bid * 256 + tid) * 4;
    float m = qm[i >> 10];
    float4 vv = *(const float4*)(q + i);
    short4v o;
    o.x = (short)f2bf(vv.x * m);
    o.y = (short)f2bf(vv.y * m);
    o.z = (short)f2bf(vv.z * m);
    o.w = (short)f2bf(vv.w * m);
    *(short4v*)(Qc + i) = o;
  } else if (bid < 9216) {
    // k&v rows [1920,2048) per batch, * mask -> bf16
    int zb = bid - 8192;
    int z = zb >> 9;  // 0=k, 1=v (512 blocks each)
    int bx = zb & 511;
    const float* src = z ? v : k;
    const float* mask = z ? vm : km;
    u16* dst = z ? Vc : Kc;
    int i = (bx * 256 + tid) * 4;
    int r = i >> 10, c = i & 1023;
    size_t sr = (size_t)(r >> 7) * 2048 + 1920 + (r & 127);
    float m = mask[sr];
    float4 vv = *(const float4*)(src + sr * 1024 + c);
    short4v o;
    o.x = (short)f2bf(vv.x * m);
    o.y = (short)f2bf(vv.y * m);
    o.z = (short)f2bf(vv.z * m);
    o.w = (short)f2bf(vv.w * m);
    *(short4v*)(dst + i) = o;
  } else {
    // weight transpose: WT[n][k] = bf16(W[k][n]); 1024 blocks per weight
    int idx = bid - 9216;
    int z = idx >> 10;
    int rem = idx & 1023;
    const float* W = (z == 0) ? wq : (z == 1) ? wk : (z == 2) ? wv : wo;
    u16* WT = (z == 0) ? WqT : (z == 1) ? WkT : (z == 2) ? WvT : WoT;
    int tx = tid & 31, ty = tid >> 5;
    int x = (rem & 31) * 32 + tx;
    int y0 = (rem >> 5) * 32;
    for (int i = ty; i < 32; i += 8)
      tile[i][tx] = f2bf(W[(size_t)(y0 + i) * 1024 + x]);
    __syncthreads();
    int x2 = y0 + tx;
    int r0 = (rem & 31) * 32;
    for (int i = ty; i < 32; i += 8)
      WT[(size_t)(r0 + i) * 1024 + x2] = tile[tx][i];
  }
}

// ---- m97-style 128x128 tiled GEMM body: C = A @ BT^T + bias ----
// OUTMODE 0: bf16 C[r*N+c] ; 1: bf16 FK (b,h,l,d) ; 2: bf16 FVT (b,h,d,l) ;
// 3: fp32 C[r*N+c]
// OUTMODE is a TEMPLATE param: runtime outmode (round 7) spilled the
// accumulator to scratch (974 MB writes/dispatch, VGPR 84, 235 us).
template <int OUTMODE>
__device__ __forceinline__ void gemm_body(
    const u16* __restrict__ A, const u16* __restrict__ BT,
    const float* __restrict__ bias, void* __restrict__ Cv, int N, int K,
    int bx, int by) {
  __shared__ u16 As[128 * 32];  // [row][k], BK=32
  __shared__ u16 Bs[128 * 32];  // [col][k]
  const int wave = threadIdx.x >> 6, lane = threadIdx.x & 63;
  const int ln = lane & 15, quad = lane >> 4;
  const int w0 = wave & 1, w1 = wave >> 1;
  const int row0 = bx * 128;
  const int col0 = by * 128;
  const int srow = lane >> 2, scol = (lane & 3) * 8;
  const u16* gA = A + (size_t)(row0 + wave * 32 + srow) * K + scol;
  const u16* gB = BT + (size_t)(col0 + wave * 32 + srow) * K + scol;
  u16* lA = &As[(wave * 32) * 32];
  u16* lB = &Bs[(wave * 32) * 32];

  f32x4 acc[4][4];
  for (int i = 0; i < 4; ++i)
    for (int j = 0; j < 4; ++j) acc[i][j] = f32x4{0.f, 0.f, 0.f, 0.f};

  for (int k0 = 0; k0 < K; k0 += 32) {
    async_ld16(gA + k0, lA);
    async_ld16(gA + (size_t)16 * K + k0, lA + 16 * 32);
    async_ld16(gB + k0, lB);
    async_ld16(gB + (size_t)16 * K + k0, lB + 16 * 32);
    __syncthreads();
    short8 af[4], bf[4];
    for (int mt = 0; mt < 4; ++mt)
      af[mt] = *(const short8*)&As[(w1 * 64 + mt * 16 + ln) * 32 + quad * 8];
    for (int nt = 0; nt < 4; ++nt)
      bf[nt] = *(const short8*)&Bs[(w0 * 64 + nt * 16 + ln) * 32 + quad * 8];
    for (int mt = 0; mt < 4; ++mt)
      for (int nt = 0; nt < 4; ++nt)
        acc[mt][nt] = __builtin_amdgcn_mfma_f32_16x16x32_bf16(af[mt], bf[nt],
                                                              acc[mt][nt], 0, 0, 0);
    __syncthreads();
  }

  for (int nt = 0; nt < 4; ++nt) {
    int c = col0 + w0 * 64 + nt * 16 + ln;
    float bval = bias ? bias[c] : 0.f;
    for (int mt = 0; mt < 4; ++mt)
      for (int reg = 0; reg < 4; ++reg) {
        int r = row0 + w1 * 64 + mt * 16 + quad * 4 + reg;
        float val = acc[mt][nt][reg] + bval;
        if (OUTMODE == 3) {
          ((float*)Cv)[(size_t)r * N + c] = val;
        } else if (OUTMODE == 0) {
          ((u16*)Cv)[(size_t)r * N + c] = f2bf(val);
        } else if (OUTMODE == 1) {
          size_t idx = ((size_t)(r >> 7) << 17) + ((size_t)(c >> 6) << 13) +
                       ((size_t)(r & 127) << 6) + (c & 63);
          ((u16*)Cv)[idx] = f2bf(val);
        } else {
          size_t idx = ((size_t)(r >> 7) << 17) + ((size_t)(c >> 6) << 13) +
                       ((size_t)(c & 63) << 7) + (r & 127);
          ((u16*)Cv)[idx] = f2bf(val);
        }
      }
  }
}

// Fused Q/K/V projection launch: 576 blocks, XCD-swizzled (576 % 8 == 0).
// swizzled id < 512 -> Q tile (64x8); 512-543 K tiles; 544-575 V tiles.
// Each branch inlines a compile-time-specialized gemm_body clone.
__global__ __launch_bounds__(256) void proj(
    const u16* __restrict__ Qc, const u16* __restrict__ Kc,
    const u16* __restrict__ Vc, const u16* __restrict__ WqT,
    const u16* __restrict__ WkT, const u16* __restrict__ WvT,
    const float* __restrict__ bq, const float* __restrict__ bk,
    const float* __restrict__ bv, u16* __restrict__ Qws, u16* __restrict__ FK,
    u16* __restrict__ FVT) {
  int orig = blockIdx.x;                   // [0,576)
  int id = (orig & 7) * 72 + (orig >> 3);  // bijective XCD swizzle
  if (id < 512) {
    gemm_body<0>(Qc, WqT, bq, Qws, 1024, 1024, id >> 3, id & 7);
  } else if (id < 544) {
    int t = id - 512;
    gemm_body<1>(Kc, WkT, bk, FK, 1024, 1024, t >> 3, t & 7);
  } else {
    int t = id - 544;
    gemm_body<2>(Vc, WvT, bv, FVT, 1024, 1024, t >> 3, t & 7);
  }
}

// Output projection: 512 blocks linear, XCD-swizzled (512 % 8 == 0).
__global__ __launch_bounds__(256) void gemm_o(const u16* __restrict__ A,
                                              const u16* __restrict__ BT,
                                              const float* __restrict__ bias,
                                              float* __restrict__ C) {
  int orig = blockIdx.x;                   // [0,512)
  int id = (orig & 7) * 64 + (orig >> 3);  // bijective XCD swizzle
  gemm_body<3>(A, BT, bias, C, 1024, 1024, id >> 3, id & 7);
}

// Fused attention: per (b,h) and 16-row Q tile (4 tiles/block), no barriers.
__global__ __launch_bounds__(256) void attn_kernel(
    const u16* __restrict__ Q, const u16* __restrict__ FK,
    const u16* __restrict__ FVT, float* __restrict__ attn_out,
    u16* __restrict__ OUTP) {
  __shared__ float lds[4][16 * 132];  // P, padded row stride 132 (2-way max)
  const int wave = threadIdx.x >> 6, lane = threadIdx.x & 63;
  const int ln = lane & 15, quad = lane >> 4;
  const int bh = blockIdx.x, b = bh >> 4, h = bh & 15;
  const int q0 = blockIdx.y * 64 + wave * 16;

  const u16* qp = Q + (size_t)(b * 2048 + q0 + ln) * 1024 + h * 64 + quad * 8;
  const u16* fk = FK + ((size_t)bh << 13);
  const u16* fvt = FVT + ((size_t)bh << 13);

  f32x4 acc[8];
  for (int i = 0; i < 8; ++i) acc[i] = f32x4{0.f, 0.f, 0.f, 0.f};
  for (int ks = 0; ks < 2; ++ks) {
    short8 a = *(const short8*)(qp + ks * 32);
    __builtin_amdgcn_s_setprio(1);
    for (int nt = 0; nt < 8; ++nt) {
      short8 bfrag = *(const short8*)(fk + (size_t)(nt * 16 + ln) * 64 +
                                      ks * 32 + quad * 8);
      acc[nt] = __builtin_amdgcn_mfma_f32_16x16x32_bf16(a, bfrag, acc[nt], 0, 0, 0);
    }
    __builtin_amdgcn_s_setprio(0);
  }
  float mx[4] = {-3e38f, -3e38f, -3e38f, -3e38f};
  for (int nt = 0; nt < 8; ++nt) {
    int l = nt * 16 + ln;
    for (int reg = 0; reg < 4; ++reg) {
      int qg = q0 + quad * 4 + reg;
      float vv = acc[nt][reg] * 0.125f;
      if (l > qg) vv = -1e9f;
      acc[nt][reg] = vv;
      mx[reg] = fmaxf(mx[reg], vv);
    }
  }
  for (int off = 1; off < 16; off <<= 1)
    for (int reg = 0; reg < 4; ++reg)
      mx[reg] = fmaxf(mx[reg], __shfl_xor(mx[reg], off, 64));
  float sm[4] = {0.f, 0.f, 0.f, 0.f};
  for (int nt = 0; nt < 8; ++nt)
    for (int reg = 0; reg < 4; ++reg) {
      float p = __expf(acc[nt][reg] - mx[reg]);
      acc[nt][reg] = p;
      sm[reg] += p;
    }
  for (int off = 1; off < 16; off <<= 1)
    for (int reg = 0; reg < 4; ++reg) sm[reg] += __shfl_xor(sm[reg], off, 64);
  float inv[4];
  for (int reg = 0; reg < 4; ++reg) inv[reg] = 1.f / sm[reg];
  // P -> LDS (wave-local; padded stride kills 4-way write conflicts)
  for (int nt = 0; nt < 8; ++nt)
    for (int reg = 0; reg < 4; ++reg)
      lds[wave][(quad * 4 + reg) * 132 + nt * 16 + ln] = acc[nt][reg] * inv[reg];
  // attn output (fp32), vectorized from LDS
  {
    int r = lane >> 2, cb = (lane & 3) * 32;
    const float* lrow = &lds[wave][r * 132 + cb];
    float* dst = attn_out + ((size_t)bh * 2048 + q0 + r) * 128 + cb;
    for (int vblk = 0; vblk < 8; ++vblk)
      *(float4*)(dst + vblk * 4) = *(const float4*)(lrow + vblk * 4);
  }
  // PV: out(16x64) = P(16x128) @ FV(128x64)
  f32x4 o[4];
  for (int i = 0; i < 4; ++i) o[i] = f32x4{0.f, 0.f, 0.f, 0.f};
  for (int kk = 0; kk < 4; ++kk) {
    const float* apf = &lds[wave][ln * 132 + kk * 32 + quad * 8];
    float2 f01 = *(const float2*)(apf + 0);
    float2 f23 = *(const float2*)(apf + 2);
    float2 f45 = *(const float2*)(apf + 4);
    float2 f67 = *(const float2*)(apf + 6);
    short8 a;
    a[0] = (short)f2bf(f01.x);
    a[1] = (short)f2bf(f01.y);
    a[2] = (short)f2bf(f23.x);
    a[3] = (short)f2bf(f23.y);
    a[4] = (short)f2bf(f45.x);
    a[5] = (short)f2bf(f45.y);
    a[6] = (short)f2bf(f67.x);
    a[7] = (short)f2bf(f67.y);
    __builtin_amdgcn_s_setprio(1);
    for (int nt = 0; nt < 4; ++nt) {
      short8 bfrag = *(const short8*)(fvt + (size_t)(nt * 16 + ln) * 128 +
                                      kk * 32 + quad * 8);
      o[nt] = __builtin_amdgcn_mfma_f32_16x16x32_bf16(a, bfrag, o[nt], 0, 0, 0);
    }
    __builtin_amdgcn_s_setprio(0);
  }
  // stage o as bf16 in (reused) wave-local LDS, stride 72 u16 (16B-aligned rows)
  {
    u16* ot = (u16*)&lds[wave][0];
    for (int nt = 0; nt < 4; ++nt)
      for (int reg = 0; reg < 4; ++reg)
        ot[(quad * 4 + reg) * 72 + nt * 16 + ln] = f2bf(o[nt][reg]);
    int row = lane >> 2;
    u16* dst = OUTP + (size_t)(b * 2048 + q0 + row) * 1024 + h * 64;
    for (int p = 0; p < 2; ++p) {
      int col = p * 32 + (lane & 3) * 8;
      *(short8*)(dst + col) = *(const short8*)&ot[row * 72 + col];
    }
  }
}

extern "C" void kernel_launch(void* const* d_in, const int* in_sizes, int n_in,
                              void* d_out, int out_size, void* d_ws,
                              size_t ws_size, hipStream_t stream) {
  const float* q = (const float*)d_in[0];
  const float* k = (const float*)d_in[1];
  const float* v = (const float*)d_in[2];
  const float* qm = (const float*)d_in[3];
  const float* km = (const float*)d_in[4];
  const float* vm = (const float*)d_in[5];
  const float* wq = (const float*)d_in[6];
  const float* bq = (const float*)d_in[7];
  const float* wk = (const float*)d_in[8];
  const float* bk = (const float*)d_in[9];
  const float* wv = (const float*)d_in[10];
  const float* bv = (const float*)d_in[11];
  const float* wo = (const float*)d_in[12];
  const float* bo = (const float*)d_in[13];
  float* out = (float*)d_out;                       // (4,2048,1024) fp32
  float* attn_out = out + (size_t)4 * 2048 * 1024;  // (4,16,2048,128) fp32

  char* ws = (char*)d_ws;
  const size_t MB = 1ull << 20;
  u16* WqT = (u16*)(ws + 0 * MB);
  u16* WkT = (u16*)(ws + 2 * MB);
  u16* WvT = (u16*)(ws + 4 * MB);
  u16* WoT = (u16*)(ws + 6 * MB);
  u16* Qws = (u16*)(ws + 8 * MB);    // 16 MB projected Q bf16
  u16* FKw = (u16*)(ws + 24 * MB);   // 1 MB (b,h,l,d)
  u16* FVTw = (u16*)(ws + 25 * MB);  // 1 MB (b,h,d,l)
  u16* OUTP = (u16*)(ws + 26 * MB);  // 16 MB pre-Wo bf16; aliased as Qc first
  u16* Qc = OUTP;                    // dead before OUTP written
  u16* Kc = (u16*)(ws + 42 * MB);
  u16* Vc = (u16*)(ws + 43 * MB);

  prep<<<13312, 256, 0, stream>>>(q, qm, k, km, v, vm, wq, wk, wv, wo, Qc, Kc,
                                  Vc, WqT, WkT, WvT, WoT);
  // Q + K + V projections in ONE launch (576 blocks: 512 Q tiles + 64 KV tiles)
  proj<<<576, 256, 0, stream>>>(Qc, Kc, Vc, WqT, WkT, WvT, bq, bk, bv, Qws,
                                FKw, FVTw);
  attn_kernel<<<dim3(64, 32), 256, 0, stream>>>(Qws, FKw, FVTw, attn_out, OUTP);
  // Output projection -> fp32 output 0
  gemm_o<<<512, 256, 0, stream>>>(OUTP, WoT, bo, out);
}

// Round 12
// 284.586 us; speedup vs baseline: 1.7356x; 1.0488x over previous
//
#include <hip/hip_runtime.h>

typedef unsigned short u16;
typedef unsigned int u32;
typedef __attribute__((ext_vector_type(8))) short short8;
typedef __attribute__((ext_vector_type(4))) short short4v;
typedef __attribute__((ext_vector_type(4))) float f32x4;

__device__ __forceinline__ u16 f2bf(float f) {
  union { float f; u32 u; } v; v.f = f;
  u32 u = v.u;
  u32 r = (u + 0x7fffu + ((u >> 16) & 1u)) >> 16;
  return (u16)r;
}

// async global->LDS, 16 B per lane; lds base wave-uniform, lane i -> lds+i*16B.
__device__ __forceinline__ void async_ld16(const u16* g, u16* l) {
  __builtin_amdgcn_global_load_lds(
      (const __attribute__((address_space(1))) void*)g,
      (__attribute__((address_space(3))) void*)l, 16, 0, 0);
}

// ---- fused prep: [0,8192) q-conv | [8192,9216) k/v slice conv | [9216,13312) 4 transposes
__global__ __launch_bounds__(256) void prep(
    const float* __restrict__ q, const float* __restrict__ qm,
    const float* __restrict__ k, const float* __restrict__ km,
    const float* __restrict__ v, const float* __restrict__ vm,
    const float* __restrict__ wq, const float* __restrict__ wk,
    const float* __restrict__ wv, const float* __restrict__ wo,
    u16* __restrict__ Qc, u16* __restrict__ Kc, u16* __restrict__ Vc,
    u16* __restrict__ WqT, u16* __restrict__ WkT, u16* __restrict__ WvT,
    u16* __restrict__ WoT) {
  __shared__ u16 tile[32][33];
  const int bid = blockIdx.x;
  const int tid = threadIdx.x;
  if (bid < 8192) {
    // q * mask -> bf16
    int i = (bid * 256 + tid) * 4;
    float m = qm[i >> 10];
    float4 vv = *(const float4*)(q + i);
    short4v o;
    o.x = (short)f2bf(vv.x * m);
    o.y = (short)f2bf(vv.y * m);
    o.z = (short)f2bf(vv.z * m);
    o.w = (short)f2bf(vv.w * m);
    *(short4v*)(Qc + i) = o;
  } else if (bid < 9216) {
    // k&v rows [1920,2048) per batch, * mask -> bf16
    int zb = bid - 8192;
    int z = zb >> 9;  // 0=k, 1=v (512 blocks each)
    int bx = zb & 511;
    const float* src = z ? v : k;
    const float* mask = z ? vm : km;
    u16* dst = z ? Vc : Kc;
    int i = (bx * 256 + tid) * 4;
    int r = i >> 10, c = i & 1023;
    size_t sr = (size_t)(r >> 7) * 2048 + 1920 + (r & 127);
    float m = mask[sr];
    float4 vv = *(const float4*)(src + sr * 1024 + c);
    short4v o;
    o.x = (short)f2bf(vv.x * m);
    o.y = (short)f2bf(vv.y * m);
    o.z = (short)f2bf(vv.z * m);
    o.w = (short)f2bf(vv.w * m);
    *(short4v*)(dst + i) = o;
  } else {
    // weight transpose: WT[n][k] = bf16(W[k][n]); 1024 blocks per weight
    int idx = bid - 9216;
    int z = idx >> 10;
    int rem = idx & 1023;
    const float* W = (z == 0) ? wq : (z == 1) ? wk : (z == 2) ? wv : wo;
    u16* WT = (z == 0) ? WqT : (z == 1) ? WkT : (z == 2) ? WvT : WoT;
    int tx = tid & 31, ty = tid >> 5;
    int x = (rem & 31) * 32 + tx;
    int y0 = (rem >> 5) * 32;
    for (int i = ty; i < 32; i += 8)
      tile[i][tx] = f2bf(W[(size_t)(y0 + i) * 1024 + x]);
    __syncthreads();
    int x2 = y0 + tx;
    int r0 = (rem & 31) * 32;
    for (int i = ty; i < 32; i += 8)
      WT[(size_t)(r0 + i) * 1024 + x2] = tile[tx][i];
  }
}

// ---- m97-style 128x128 tiled GEMM body: C = A @ BT^T + bias ----
// OUTMODE 0: bf16 C[r*N+c] ; 1: bf16 FK (b,h,l,d) ; 2: bf16 FVT (b,h,d,l) ;
// 3: fp32 C[r*N+c]
// OUTMODE is a TEMPLATE param: runtime outmode (round 7) spilled the
// accumulator to scratch (974 MB writes/dispatch, VGPR 84, 235 us).
template <int OUTMODE>
__device__ __forceinline__ void gemm_body(
    const u16* __restrict__ A, const u16* __restrict__ BT,
    const float* __restrict__ bias, void* __restrict__ Cv, int N, int K,
    int bx, int by) {
  __shared__ u16 As[128 * 32];  // [row][k], BK=32
  __shared__ u16 Bs[128 * 32];  // [col][k]
  const int wave = threadIdx.x >> 6, lane = threadIdx.x & 63;
  const int ln = lane & 15, quad = lane >> 4;
  const int w0 = wave & 1, w1 = wave >> 1;
  const int row0 = bx * 128;
  const int col0 = by * 128;
  const int srow = lane >> 2, scol = (lane & 3) * 8;
  const u16* gA = A + (size_t)(row0 + wave * 32 + srow) * K + scol;
  const u16* gB = BT + (size_t)(col0 + wave * 32 + srow) * K + scol;
  u16* lA = &As[(wave * 32) * 32];
  u16* lB = &Bs[(wave * 32) * 32];

  f32x4 acc[4][4];
  for (int i = 0; i < 4; ++i)
    for (int j = 0; j < 4; ++j) acc[i][j] = f32x4{0.f, 0.f, 0.f, 0.f};

  for (int k0 = 0; k0 < K; k0 += 32) {
    async_ld16(gA + k0, lA);
    async_ld16(gA + (size_t)16 * K + k0, lA + 16 * 32);
    async_ld16(gB + k0, lB);
    async_ld16(gB + (size_t)16 * K + k0, lB + 16 * 32);
    __syncthreads();
    short8 af[4], bf[4];
    for (int mt = 0; mt < 4; ++mt)
      af[mt] = *(const short8*)&As[(w1 * 64 + mt * 16 + ln) * 32 + quad * 8];
    for (int nt = 0; nt < 4; ++nt)
      bf[nt] = *(const short8*)&Bs[(w0 * 64 + nt * 16 + ln) * 32 + quad * 8];
    for (int mt = 0; mt < 4; ++mt)
      for (int nt = 0; nt < 4; ++nt)
        acc[mt][nt] = __builtin_amdgcn_mfma_f32_16x16x32_bf16(af[mt], bf[nt],
                                                              acc[mt][nt], 0, 0, 0);
    __syncthreads();
  }

  for (int nt = 0; nt < 4; ++nt) {
    int c = col0 + w0 * 64 + nt * 16 + ln;
    float bval = bias ? bias[c] : 0.f;
    for (int mt = 0; mt < 4; ++mt)
      for (int reg = 0; reg < 4; ++reg) {
        int r = row0 + w1 * 64 + mt * 16 + quad * 4 + reg;
        float val = acc[mt][nt][reg] + bval;
        if (OUTMODE == 3) {
          ((float*)Cv)[(size_t)r * N + c] = val;
        } else if (OUTMODE == 0) {
          ((u16*)Cv)[(size_t)r * N + c] = f2bf(val);
        } else if (OUTMODE == 1) {
          size_t idx = ((size_t)(r >> 7) << 17) + ((size_t)(c >> 6) << 13) +
                       ((size_t)(r & 127) << 6) + (c & 63);
          ((u16*)Cv)[idx] = f2bf(val);
        } else {
          size_t idx = ((size_t)(r >> 7) << 17) + ((size_t)(c >> 6) << 13) +
                       ((size_t)(c & 63) << 7) + (r & 127);
          ((u16*)Cv)[idx] = f2bf(val);
        }
      }
  }
}

// Fused Q/K/V projection launch: 576 blocks, XCD-swizzled (576 % 8 == 0).
// swizzled id < 512 -> Q tile (64x8); 512-543 K tiles; 544-575 V tiles.
__global__ __launch_bounds__(256) void proj(
    const u16* __restrict__ Qc, const u16* __restrict__ Kc,
    const u16* __restrict__ Vc, const u16* __restrict__ WqT,
    const u16* __restrict__ WkT, const u16* __restrict__ WvT,
    const float* __restrict__ bq, const float* __restrict__ bk,
    const float* __restrict__ bv, u16* __restrict__ Qws, u16* __restrict__ FK,
    u16* __restrict__ FVT) {
  int orig = blockIdx.x;                   // [0,576)
  int id = (orig & 7) * 72 + (orig >> 3);  // bijective XCD swizzle
  if (id < 512) {
    gemm_body<0>(Qc, WqT, bq, Qws, 1024, 1024, id >> 3, id & 7);
  } else if (id < 544) {
    int t = id - 512;
    gemm_body<1>(Kc, WkT, bk, FK, 1024, 1024, t >> 3, t & 7);
  } else {
    int t = id - 544;
    gemm_body<2>(Vc, WvT, bv, FVT, 1024, 1024, t >> 3, t & 7);
  }
}

// Output projection: 512 blocks linear, XCD-swizzled (512 % 8 == 0).
// NOTE (round 10): hipLaunchCooperativeKernel + grid.sync() fusion of attn+Wo
// FAILED under the harness's graph capture (out buffer stayed zero, absmax ==
// max|ref|). Keep this a separate normal launch.
__global__ __launch_bounds__(256) void gemm_o(const u16* __restrict__ A,
                                              const u16* __restrict__ BT,
                                              const float* __restrict__ bias,
                                              float* __restrict__ C) {
  int orig = blockIdx.x;                   // [0,512)
  int id = (orig & 7) * 64 + (orig >> 3);  // bijective XCD swizzle
  gemm_body<3>(A, BT, bias, C, 1024, 1024, id >> 3, id & 7);
}

// Fused attention: per (b,h) and 16-row Q tile (4 tiles/block), no barriers.
// Round-11 rework: bf16 P staged in LDS (17.4 KB vs 33.8 KB fp32);
// attn_out written directly from registers (same fp32 bits, 64B segments);
// PV A-fragment is one ds_read_b128 per kk (no fp32 reload + f2bf).
__global__ __launch_bounds__(256) void attn_kernel(
    const u16* __restrict__ Q, const u16* __restrict__ FK,
    const u16* __restrict__ FVT, float* __restrict__ attn_out,
    u16* __restrict__ OUTP) {
  __shared__ u16 pbuf[4][16 * 136];  // bf16 P; stride 136 (rows 16B-aligned, pad)
  const int wave = threadIdx.x >> 6, lane = threadIdx.x & 63;
  const int ln = lane & 15, quad = lane >> 4;
  const int bh = blockIdx.x, b = bh >> 4, h = bh & 15;
  const int q0 = blockIdx.y * 64 + wave * 16;

  const u16* qp = Q + (size_t)(b * 2048 + q0 + ln) * 1024 + h * 64 + quad * 8;
  const u16* fk = FK + ((size_t)bh << 13);
  const u16* fvt = FVT + ((size_t)bh << 13);

  f32x4 acc[8];
  for (int i = 0; i < 8; ++i) acc[i] = f32x4{0.f, 0.f, 0.f, 0.f};
  for (int ks = 0; ks < 2; ++ks) {
    short8 a = *(const short8*)(qp + ks * 32);
    __builtin_amdgcn_s_setprio(1);
    for (int nt = 0; nt < 8; ++nt) {
      short8 bfrag = *(const short8*)(fk + (size_t)(nt * 16 + ln) * 64 +
                                      ks * 32 + quad * 8);
      acc[nt] = __builtin_amdgcn_mfma_f32_16x16x32_bf16(a, bfrag, acc[nt], 0, 0, 0);
    }
    __builtin_amdgcn_s_setprio(0);
  }
  float mx[4] = {-3e38f, -3e38f, -3e38f, -3e38f};
  for (int nt = 0; nt < 8; ++nt) {
    int l = nt * 16 + ln;
    for (int reg = 0; reg < 4; ++reg) {
      int qg = q0 + quad * 4 + reg;
      float vv = acc[nt][reg] * 0.125f;
      if (l > qg) vv = -1e9f;
      acc[nt][reg] = vv;
      mx[reg] = fmaxf(mx[reg], vv);
    }
  }
  for (int off = 1; off < 16; off <<= 1)
    for (int reg = 0; reg < 4; ++reg)
      mx[reg] = fmaxf(mx[reg], __shfl_xor(mx[reg], off, 64));
  float sm[4] = {0.f, 0.f, 0.f, 0.f};
  for (int nt = 0; nt < 8; ++nt)
    for (int reg = 0; reg < 4; ++reg) {
      float p = __expf(acc[nt][reg] - mx[reg]);
      acc[nt][reg] = p;
      sm[reg] += p;
    }
  for (int off = 1; off < 16; off <<= 1)
    for (int reg = 0; reg < 4; ++reg) sm[reg] += __shfl_xor(sm[reg], off, 64);
  float inv[4];
  for (int reg = 0; reg < 4; ++reg) inv[reg] = 1.f / sm[reg];
  // attn_out (fp32) straight from registers (rows quad*4+reg, cols nt*16+ln:
  // each store = 4 x 64B segments per wave) + bf16 P to LDS for PV.
  {
    float* ao = attn_out + ((size_t)bh * 2048 + q0 + quad * 4) * 128 + ln;
    u16* pw = &pbuf[wave][(quad * 4) * 136 + ln];
    for (int nt = 0; nt < 8; ++nt)
      for (int reg = 0; reg < 4; ++reg) {
        float pv = acc[nt][reg] * inv[reg];
        ao[(size_t)reg * 128 + nt * 16] = pv;
        pw[reg * 136 + nt * 16] = f2bf(pv);
      }
  }
  // PV: out(16x64) = P(16x128) @ FV(128x64); A-frag = 1 ds_read_b128 per kk
  // (wave-local LDS: same-wave write->read needs no barrier).
  f32x4 o[4];
  for (int i = 0; i < 4; ++i) o[i] = f32x4{0.f, 0.f, 0.f, 0.f};
  for (int kk = 0; kk < 4; ++kk) {
    short8 a = *(const short8*)&pbuf[wave][ln * 136 + kk * 32 + quad * 8];
    __builtin_amdgcn_s_setprio(1);
    for (int nt = 0; nt < 4; ++nt) {
      short8 bfrag = *(const short8*)(fvt + (size_t)(nt * 16 + ln) * 128 +
                                      kk * 32 + quad * 8);
      o[nt] = __builtin_amdgcn_mfma_f32_16x16x32_bf16(a, bfrag, o[nt], 0, 0, 0);
    }
    __builtin_amdgcn_s_setprio(0);
  }
  // stage o as bf16 in (reused) wave-local LDS, stride 72 u16 (16B-aligned rows)
  {
    u16* ot = &pbuf[wave][0];  // P dead after PV; 16*72=1152 <= 2176 elems
    for (int nt = 0; nt < 4; ++nt)
      for (int reg = 0; reg < 4; ++reg)
        ot[(quad * 4 + reg) * 72 + nt * 16 + ln] = f2bf(o[nt][reg]);
    int row = lane >> 2;
    u16* dst = OUTP + (size_t)(b * 2048 + q0 + row) * 1024 + h * 64;
    for (int p = 0; p < 2; ++p) {
      int col = p * 32 + (lane & 3) * 8;
      *(short8*)(dst + col) = *(const short8*)&ot[row * 72 + col];
    }
  }
}

extern "C" void kernel_launch(void* const* d_in, const int* in_sizes, int n_in,
                              void* d_out, int out_size, void* d_ws,
                              size_t ws_size, hipStream_t stream) {
  const float* q = (const float*)d_in[0];
  const float* k = (const float*)d_in[1];
  const float* v = (const float*)d_in[2];
  const float* qm = (const float*)d_in[3];
  const float* km = (const float*)d_in[4];
  const float* vm = (const float*)d_in[5];
  const float* wq = (const float*)d_in[6];
  const float* bq = (const float*)d_in[7];
  const float* wk = (const float*)d_in[8];
  const float* bk = (const float*)d_in[9];
  const float* wv = (const float*)d_in[10];
  const float* bv = (const float*)d_in[11];
  const float* wo = (const float*)d_in[12];
  const float* bo = (const float*)d_in[13];
  float* out = (float*)d_out;                       // (4,2048,1024) fp32
  float* attn_out = out + (size_t)4 * 2048 * 1024;  // (4,16,2048,128) fp32

  char* ws = (char*)d_ws;
  const size_t MB = 1ull << 20;
  u16* WqT = (u16*)(ws + 0 * MB);
  u16* WkT = (u16*)(ws + 2 * MB);
  u16* WvT = (u16*)(ws + 4 * MB);
  u16* WoT = (u16*)(ws + 6 * MB);
  u16* Qws = (u16*)(ws + 8 * MB);    // 16 MB projected Q bf16
  u16* FKw = (u16*)(ws + 24 * MB);   // 1 MB (b,h,l,d)
  u16* FVTw = (u16*)(ws + 25 * MB);  // 1 MB (b,h,d,l)
  u16* OUTP = (u16*)(ws + 26 * MB);  // 16 MB pre-Wo bf16; aliased as Qc first
  u16* Qc = OUTP;                    // dead before OUTP written
  u16* Kc = (u16*)(ws + 42 * MB);
  u16* Vc = (u16*)(ws + 43 * MB);

  prep<<<13312, 256, 0, stream>>>(q, qm, k, km, v, vm, wq, wk, wv, wo, Qc, Kc,
                                  Vc, WqT, WkT, WvT, WoT);
  // Q + K + V projections in ONE launch (576 blocks: 512 Q tiles + 64 KV tiles)
  proj<<<576, 256, 0, stream>>>(Qc, Kc, Vc, WqT, WkT, WvT, bq, bk, bv, Qws,
                                FKw, FVTw);
  attn_kernel<<<dim3(64, 32), 256, 0, stream>>>(Qws, FKw, FVTw, attn_out, OUTP);
  // Output projection -> fp32 output 0
  gemm_o<<<512, 256, 0, stream>>>(OUTP, WoT, bo, out);
}